// Round 1
// baseline (287.335 us; speedup 1.0000x reference)
//
#include <hip/hip_runtime.h>
#include <float.h>
#include <stdint.h>

#define EPSF 1e-6f

constexpr int Dc = 512, Kc = 4096, DOc = 1024;
constexpr int Mc = 16384;                 // 4*4096 rows
constexpr int NHALF = 2048;               // centers per half-pass

typedef _Float16 f16x8 __attribute__((ext_vector_type(8)));
typedef float f32x4 __attribute__((ext_vector_type(4)));
typedef __attribute__((address_space(1))) unsigned int gu32;
typedef __attribute__((address_space(3))) unsigned int lu32;
typedef unsigned long long u64;

// ---------- convert x: f16 cast + per-row candidate window ----------
__global__ __launch_bounds__(256) void cvt_x_kernel(const float* __restrict__ x,
                                                    _Float16* __restrict__ xh,
                                                    unsigned* __restrict__ wthr) {
  const int lane = threadIdx.x & 63, w = threadIdx.x >> 6;
  const int row = blockIdx.x * 4 + w;
  const size_t base = (size_t)row * Dc + lane * 8;
  float4 v0 = *(const float4*)(x + base);
  float4 v1 = *(const float4*)(x + base + 4);
  float v[8] = {v0.x, v0.y, v0.z, v0.w, v1.x, v1.y, v1.z, v1.w};
  f16x8 h;
  float s = 0.f;
#pragma unroll
  for (int i = 0; i < 8; ++i) {
    const float q = v[i] + EPSF;
    h[i] = (_Float16)q;
    s += q * q;
  }
  *(f16x8*)(xh + base) = h;
#pragma unroll
  for (int m = 1; m < 64; m <<= 1) s += __shfl_xor(s, m, 64);
  // window (u16 quant units): 64*[2(2e+e^2)*||c||max*||x||] + slack; e=2^-11
  if (lane == 0) wthr[row] = (unsigned)(2.829f * sqrtf(s) + 8.0f);
}

__global__ __launch_bounds__(256) void cvt_c_kernel(const float* __restrict__ centers,
                                                    _Float16* __restrict__ ch,
                                                    float* __restrict__ c2) {
  const int lane = threadIdx.x & 63, w = threadIdx.x >> 6;
  const int row = blockIdx.x * 4 + w;
  const size_t base = (size_t)row * Dc + lane * 8;
  float4 v0 = *(const float4*)(centers + base);
  float4 v1 = *(const float4*)(centers + base + 4);
  float v[8] = {v0.x, v0.y, v0.z, v0.w, v1.x, v1.y, v1.z, v1.w};
  f16x8 h;
  float s = 0.f;
#pragma unroll
  for (int i = 0; i < 8; ++i) { s += v[i] * v[i]; h[i] = (_Float16)v[i]; }
  *(f16x8*)(ch + base) = h;
#pragma unroll
  for (int off = 32; off > 0; off >>= 1) s += __shfl_down(s, off, 64);
  if (lane == 0) c2[row] = s;
}

__global__ __launch_bounds__(256) void cvt_w_kernel(const float* __restrict__ W,
                                                    _Float16* __restrict__ whT) {
  const int g = blockIdx.x * 256 + threadIdx.x;
  const int n = g & (DOc - 1), d8 = g >> 10;
  f16x8 h;
#pragma unroll
  for (int r = 0; r < 8; ++r) h[r] = (_Float16)W[(size_t)(d8 * 8 + r) * DOc + n];
  *(f16x8*)(whT + (size_t)n * Dc + d8 * 8) = h;
}

// ---------- distance GEMM (2-phase double-buffered) + u16 quantized store ----------
__global__ __launch_bounds__(256, 2) void dist_hh_kernel(
    const _Float16* __restrict__ xh, const _Float16* __restrict__ chh,
    const float* __restrict__ c2h, unsigned short* __restrict__ dq) {
  constexpr int BM = 128, BN = 128, BK = 32;
  constexpr int BUF = BM * BK + BN * BK;            // 8192 f16 per buffer
  constexpr int TS = 136;                           // padded u16 row stride (272B, 16B-aligned)
  __shared__ __align__(16) _Float16 smem[2 * BUF];  // 32 KB: dbuf A|B; reused as u16 tile
  unsigned short* t = (unsigned short*)smem;        // [64][TS] u16 (17.4 KB)

  const int tid = threadIdx.x;
  const int lane = tid & 63, w = tid >> 6;
  const int n0 = blockIdx.x * BN;
  const int row0 = blockIdx.y * BM;
  const int srow = w * 16 + (lane >> 2);
  const int scol = (lane & 3) * 8;
  const int fr = lane & 15, kq = lane >> 4;
  const int m0 = w * 32;

  f32x4 acc[2][8];
#pragma unroll
  for (int i = 0; i < 2; ++i)
#pragma unroll
    for (int j = 0; j < 8; ++j) acc[i][j] = (f32x4){0.f, 0.f, 0.f, 0.f};

  auto stage = [&](int buf, int d0) {
    _Float16* sA_ = smem + buf * BUF;
    _Float16* sB_ = sA_ + BM * BK;
#pragma unroll
    for (int r = 0; r < 2; ++r) {
      const int rr = r * 64 + srow;
      const size_t gA = (size_t)(row0 + rr) * Dc + d0 + scol;
      const size_t gB = (size_t)(n0 + rr) * Dc + d0 + scol;
      const int lo = rr * BK + scol;
      __builtin_amdgcn_global_load_lds((const gu32*)(xh + gA), (lu32*)(sA_ + lo), 16, 0, 0);
      __builtin_amdgcn_global_load_lds((const gu32*)(chh + gB), (lu32*)(sB_ + lo), 16, 0, 0);
    }
  };

  constexpr int NSTEP = Dc / BK;  // 16
  stage(0, 0);
  __syncthreads();  // buf0 ready
  int cur = 0;
  for (int step = 0; step < NSTEP; ++step) {
    if (step + 1 < NSTEP) stage(cur ^ 1, (step + 1) * BK);  // in flight across MFMA

    const _Float16* sA = smem + cur * BUF;
    const _Float16* sB = sA + BM * BK;
    f16x8 a[2], b[8];
#pragma unroll
    for (int i = 0; i < 2; ++i)
      a[i] = *(const f16x8*)&sA[(m0 + 16 * i + fr) * BK + kq * 8];
#pragma unroll
    for (int j = 0; j < 8; ++j)
      b[j] = *(const f16x8*)&sB[(16 * j + fr) * BK + kq * 8];
#pragma unroll
    for (int i = 0; i < 2; ++i)
#pragma unroll
      for (int j = 0; j < 8; ++j)
        acc[i][j] = __builtin_amdgcn_mfma_f32_16x16x32_f16(a[i], b[j], acc[i][j], 0, 0, 0);

    __syncthreads();  // drains next-stage vmcnt (overlapped) + read-done barrier
    cur ^= 1;
  }

  // epilogue: d~ = c2[n] - 2*dot, quantize u16 (step 1/32, offset 256),
  // LDS transpose (stride TS to avoid bank conflicts) to coalesced stores.
  float c2v[8];
#pragma unroll
  for (int j = 0; j < 8; ++j) c2v[j] = c2h[n0 + 16 * j + fr];

#pragma unroll
  for (int i = 0; i < 2; ++i) {
    __syncthreads();
#pragma unroll
    for (int reg = 0; reg < 4; ++reg) {
      const int lrow = w * 16 + kq * 4 + reg;
#pragma unroll
      for (int j = 0; j < 8; ++j) {
        const float d = c2v[j] - 2.0f * acc[i][j][reg];
        int u = __float2int_rn((d + 256.0f) * 32.0f);
        u = min(65535, max(0, u));
        t[lrow * TS + 16 * j + fr] = (unsigned short)u;
      }
    }
    __syncthreads();
#pragma unroll
    for (int cc = 0; cc < 4; ++cc) {
      const int chk = tid + 256 * cc;
      const int lr = chk >> 4, c8 = chk & 15;
      const int grow = row0 + (lr >> 4) * 32 + 16 * i + (lr & 15);
      uint4 v = *(const uint4*)&t[lr * TS + c8 * 8];
      *(uint4*)&dq[(size_t)grow * NHALF + n0 + c8 * 8] = v;
    }
  }
}

// ---------- fused scan+refine: one wave per (row, half), NO atomics ----------
__global__ __launch_bounds__(256) void scan_refine_kernel(
    const unsigned short* __restrict__ dq, const unsigned* __restrict__ wthr,
    const float* __restrict__ x, const float* __restrict__ centers,
    int halfbase, int mode, u64* __restrict__ best) {
  const int w = threadIdx.x >> 6, l = threadIdx.x & 63;
  const int row = blockIdx.x * 4 + w;
  const unsigned short* dr = dq + (size_t)row * NHALF;

  uint4 v[4];
#pragma unroll
  for (int k = 0; k < 4; ++k) v[k] = *(const uint4*)&dr[k * 512 + l * 8];

  // wave min of this row-half
  unsigned mn = 0xFFFFu;
#pragma unroll
  for (int k = 0; k < 4; ++k) {
    const unsigned* u = (const unsigned*)&v[k];
#pragma unroll
    for (int q = 0; q < 4; ++q) {
      mn = min(mn, u[q] & 0xFFFFu);
      mn = min(mn, u[q] >> 16);
    }
  }
#pragma unroll
  for (int m = 1; m < 64; m <<= 1) mn = min(mn, (unsigned)__shfl_xor((int)mn, m, 64));
  const unsigned thr = mn + wthr[row];

  // preload x row (fp32), 8 elems/lane
  const float* xr = x + (size_t)row * Dc + l * 8;
  float4 a0 = *(const float4*)xr, a1 = *(const float4*)(xr + 4);
  const float xa[8] = {a0.x, a0.y, a0.z, a0.w, a1.x, a1.y, a1.z, a1.w};
  double xq[8];
#pragma unroll
  for (int i = 0; i < 8; ++i) xq[i] = (double)(xa[i] + EPSF);  // fp32 x+eps, as reference

  u64 bk = ~0ULL;
  // ballot over the 32 per-lane slots; every hit gets a 64-lane fp64 dot
#pragma unroll
  for (int k = 0; k < 4; ++k) {
    const unsigned* u = (const unsigned*)&v[k];
#pragma unroll
    for (int t = 0; t < 8; ++t) {
      const unsigned uv = (u[t >> 1] >> ((t & 1) * 16)) & 0xFFFFu;
      u64 m = __ballot(uv <= thr);
      while (m) {
        const int ln = __ffsll((long long)m) - 1;
        m &= m - 1;
        const int g = halfbase + k * 512 + ln * 8 + t;
        const float* cr = centers + (size_t)g * Dc + l * 8;
        float4 b0 = *(const float4*)cr, b1 = *(const float4*)(cr + 4);
        const float ca[8] = {b0.x, b0.y, b0.z, b0.w, b1.x, b1.y, b1.z, b1.w};
        double s = 0.0;
#pragma unroll
        for (int i = 0; i < 8; ++i) {
          const double cd = (double)ca[i];
          s += cd * cd - 2.0 * xq[i] * cd;
        }
#pragma unroll
        for (int mm = 1; mm < 64; mm <<= 1) s += __shfl_xor(s, mm, 64);
        // sortable key: d2' shifted positive (|d2'| << 16384), low 12 bits = idx
        const u64 key =
            ((u64)__double_as_longlong(s + 16384.0) & ~0xFFFULL) | (unsigned)g;
        bk = min(bk, key);
      }
    }
  }
  if (l == 0) {
    if (mode) bk = min(bk, best[row]);
    best[row] = bk;
  }
}

// ---------- projection: out = centers[best] @ W + b  (f16 MFMA, 2-phase dbuf) ----------
__global__ __launch_bounds__(256, 2) void proj_mfma_kernel(
    const _Float16* __restrict__ ch, const u64* __restrict__ best,
    const _Float16* __restrict__ whT, const float* __restrict__ bias,
    float* __restrict__ out) {
  constexpr int BM = 128, BN = 128, BK = 32;
  constexpr int BUF = BM * BK + BN * BK;            // 8192 f16 per buffer
  __shared__ __align__(16) _Float16 smem[2 * BUF];  // 32 KB
  __shared__ int ssel[BM];

  const int tid = threadIdx.x;
  const int lane = tid & 63, w = tid >> 6;
  const int row0 = blockIdx.x * BM;
  const int n0 = blockIdx.y * BN;
  const int srow = w * 16 + (lane >> 2);
  const int scol = (lane & 3) * 8;
  const int fr = lane & 15, kq = lane >> 4;
  const int m0 = w * 32;

  if (tid < BM) ssel[tid] = (int)(best[row0 + tid] & 0xFFFULL);
  __syncthreads();

  f32x4 acc[2][8];
#pragma unroll
  for (int i = 0; i < 2; ++i)
#pragma unroll
    for (int j = 0; j < 8; ++j) acc[i][j] = (f32x4){0.f, 0.f, 0.f, 0.f};

  auto stage = [&](int buf, int d0) {
    _Float16* sA_ = smem + buf * BUF;
    _Float16* sB_ = sA_ + BM * BK;
#pragma unroll
    for (int r = 0; r < 2; ++r) {
      const int rr = r * 64 + srow;
      const size_t gA = (size_t)ssel[rr] * Dc + d0 + scol;
      const size_t gB = (size_t)(n0 + rr) * Dc + d0 + scol;
      const int lo = rr * BK + scol;
      __builtin_amdgcn_global_load_lds((const gu32*)(ch + gA), (lu32*)(sA_ + lo), 16, 0, 0);
      __builtin_amdgcn_global_load_lds((const gu32*)(whT + gB), (lu32*)(sB_ + lo), 16, 0, 0);
    }
  };

  constexpr int NSTEP = Dc / BK;  // 16
  stage(0, 0);
  __syncthreads();  // buf0 ready
  int cur = 0;
  for (int step = 0; step < NSTEP; ++step) {
    if (step + 1 < NSTEP) stage(cur ^ 1, (step + 1) * BK);

    const _Float16* sA = smem + cur * BUF;
    const _Float16* sB = sA + BM * BK;
    f16x8 a[2], b[8];
#pragma unroll
    for (int i = 0; i < 2; ++i)
      a[i] = *(const f16x8*)&sA[(m0 + 16 * i + fr) * BK + kq * 8];
#pragma unroll
    for (int j = 0; j < 8; ++j)
      b[j] = *(const f16x8*)&sB[(16 * j + fr) * BK + kq * 8];
#pragma unroll
    for (int i = 0; i < 2; ++i)
#pragma unroll
      for (int j = 0; j < 8; ++j)
        acc[i][j] = __builtin_amdgcn_mfma_f32_16x16x32_f16(a[i], b[j], acc[i][j], 0, 0, 0);

    __syncthreads();
    cur ^= 1;
  }

#pragma unroll
  for (int j = 0; j < 8; ++j) {
    const int col = n0 + 16 * j + fr;
    const float bb = bias[col];
#pragma unroll
    for (int i = 0; i < 2; ++i)
#pragma unroll
      for (int reg = 0; reg < 4; ++reg)
        out[(size_t)(row0 + m0 + 16 * i + 4 * kq + reg) * DOc + col] =
            acc[i][j][reg] + bb;
  }
}

extern "C" void kernel_launch(void* const* d_in, const int* in_sizes, int n_in,
                              void* d_out, int out_size, void* d_ws, size_t ws_size,
                              hipStream_t stream) {
  const float* x = (const float*)d_in[0];        // [4,4096,512]
  const float* centers = (const float*)d_in[1];  // [4096,512]
  const float* W = (const float*)d_in[2];        // [512,1024]
  const float* b = (const float*)d_in[3];        // [1024]
  float* out = (float*)d_out;                    // [4,4096,1024] fp32

  // dq (u16 [16384][2048] = 67.1 MB) lives in d_out; proj overwrites it last.
  unsigned short* dq = (unsigned short*)d_out;

  // workspace (~22.3 MB)
  char* ws = (char*)d_ws;
  _Float16* xh = (_Float16*)(ws);                 // 16.78 MB
  _Float16* ch = (_Float16*)(ws + 16777216);      // 4.19 MB
  _Float16* whT = (_Float16*)(ws + 20971520);     // 1.05 MB
  float* c2 = (float*)(ws + 22020096);            // 16 KB
  unsigned* wthr = (unsigned*)(ws + 22036480);    // 64 KB
  u64* best = (u64*)(ws + 22102016);              // 128 KB

  cvt_x_kernel<<<Mc / 4, 256, 0, stream>>>(x, xh, wthr);
  cvt_c_kernel<<<Kc / 4, 256, 0, stream>>>(centers, ch, c2);
  cvt_w_kernel<<<Dc * DOc / (256 * 8), 256, 0, stream>>>(W, whT);

  for (int half = 0; half < 2; ++half) {
    const int hb = half * NHALF;
    dist_hh_kernel<<<dim3(NHALF / 128, Mc / 128), 256, 0, stream>>>(
        xh, ch + (size_t)hb * Dc, c2 + hb, dq);
    scan_refine_kernel<<<Mc / 4, 256, 0, stream>>>(dq, wthr, x, centers, hb,
                                                   half, best);
  }
  proj_mfma_kernel<<<dim3(Mc / 128, DOc / 128), 256, 0, stream>>>(ch, best, whT, b, out);
}

// Round 2
// 272.409 us; speedup vs baseline: 1.0548x; 1.0548x over previous
//
#include <hip/hip_runtime.h>
#include <float.h>
#include <stdint.h>

#define EPSF 1e-6f

constexpr int Dc = 512, Kc = 4096, DOc = 1024;
constexpr int Mc = 16384;                 // 4*4096 rows
constexpr int NHALF = 2048;               // centers per half-pass

typedef _Float16 f16x8 __attribute__((ext_vector_type(8)));
typedef float f32x4 __attribute__((ext_vector_type(4)));
typedef __attribute__((address_space(1))) unsigned int gu32;
typedef __attribute__((address_space(3))) unsigned int lu32;
typedef unsigned long long u64;

// ---------- convert x: f16 cast + per-row candidate window ----------
__global__ __launch_bounds__(256) void cvt_x_kernel(const float* __restrict__ x,
                                                    _Float16* __restrict__ xh,
                                                    unsigned* __restrict__ wthr) {
  const int lane = threadIdx.x & 63, w = threadIdx.x >> 6;
  const int row = blockIdx.x * 4 + w;
  const size_t base = (size_t)row * Dc + lane * 8;
  float4 v0 = *(const float4*)(x + base);
  float4 v1 = *(const float4*)(x + base + 4);
  float v[8] = {v0.x, v0.y, v0.z, v0.w, v1.x, v1.y, v1.z, v1.w};
  f16x8 h;
  float s = 0.f;
#pragma unroll
  for (int i = 0; i < 8; ++i) {
    const float q = v[i] + EPSF;
    h[i] = (_Float16)q;
    s += q * q;
  }
  *(f16x8*)(xh + base) = h;
#pragma unroll
  for (int m = 1; m < 64; m <<= 1) s += __shfl_xor(s, m, 64);
  // window (u16 quant units): 64*[2(2e+e^2)*||c||max*||x||] + slack; e=2^-11
  if (lane == 0) wthr[row] = (unsigned)(2.829f * sqrtf(s) + 8.0f);
}

__global__ __launch_bounds__(256) void cvt_c_kernel(const float* __restrict__ centers,
                                                    _Float16* __restrict__ ch,
                                                    float* __restrict__ c2) {
  const int lane = threadIdx.x & 63, w = threadIdx.x >> 6;
  const int row = blockIdx.x * 4 + w;
  const size_t base = (size_t)row * Dc + lane * 8;
  float4 v0 = *(const float4*)(centers + base);
  float4 v1 = *(const float4*)(centers + base + 4);
  float v[8] = {v0.x, v0.y, v0.z, v0.w, v1.x, v1.y, v1.z, v1.w};
  f16x8 h;
  float s = 0.f;
#pragma unroll
  for (int i = 0; i < 8; ++i) { s += v[i] * v[i]; h[i] = (_Float16)v[i]; }
  *(f16x8*)(ch + base) = h;
#pragma unroll
  for (int off = 32; off > 0; off >>= 1) s += __shfl_down(s, off, 64);
  if (lane == 0) c2[row] = s;
}

__global__ __launch_bounds__(256) void cvt_w_kernel(const float* __restrict__ W,
                                                    _Float16* __restrict__ whT) {
  const int g = blockIdx.x * 256 + threadIdx.x;
  const int n = g & (DOc - 1), d8 = g >> 10;
  f16x8 h;
#pragma unroll
  for (int r = 0; r < 8; ++r) h[r] = (_Float16)W[(size_t)(d8 * 8 + r) * DOc + n];
  *(f16x8*)(whT + (size_t)n * Dc + d8 * 8) = h;
}

// ---------- distance GEMM: 256x256 tile, BK=64, counted-vmcnt pipeline ----------
// T2: 16B-chunk XOR swizzle (chunk ^= row&7), pre-swizzled global source +
//     swizzled ds_read (read-side XOR folds to fr&7).
// T4: stage(t+2) between raw barriers, gate s_waitcnt vmcnt(8) (never 0 in loop).
// T5: setprio(1) around MFMA clusters.
__global__ __launch_bounds__(512, 2) void dist_hh_kernel(
    const _Float16* __restrict__ xh, const _Float16* __restrict__ chh,
    const float* __restrict__ c2h, unsigned short* __restrict__ dq) {
  constexpr int BM = 256, BN = 256, BK = 64;
  constexpr int NT = Dc / BK;  // 8 K-tiles
  constexpr int TS = 264;      // epilogue u16 row stride (528B, 16B-aligned)
  // A dbuf: 2 x [256][64] f16 (32KB each) | B dbuf same -> 128KB; epi 135168B
  __shared__ __align__(16) char smem_raw[256 * TS * 2];
  _Float16* smem = (_Float16*)smem_raw;
  unsigned short* t = (unsigned short*)smem_raw;

  const int tid = threadIdx.x;  // 0..511
  const int lane = tid & 63;
  const int wid = tid >> 6;               // 0..7
  const int wm = wid >> 1, wn = wid & 1;  // 4(M) x 2(N) wave grid
  const int fr = lane & 15, kq = lane >> 4;
  const int row0 = blockIdx.y * BM;
  const int n0 = blockIdx.x * BN;

  // staging decomposition: 512 threads cover 64 rows x 8 chunks (16B) per round
  const int sr = tid >> 3;              // row within 64-row round
  const int sc = tid & 7;               // dest chunk col
  const int csrc = sc ^ (sr & 7);       // pre-swizzled source chunk col
  const int sw = fr & 7;                // read-side swizzle constant

  f32x4 acc[4][8];
#pragma unroll
  for (int i = 0; i < 4; ++i)
#pragma unroll
    for (int j = 0; j < 8; ++j) acc[i][j] = (f32x4){0.f, 0.f, 0.f, 0.f};

  auto stage = [&](int kt) {
    const int p = kt & 1;
    const int d0 = kt * BK;
    _Float16* Ab = smem + p * 16384;
    _Float16* Bb = smem + 32768 + p * 16384;
#pragma unroll
    for (int ld = 0; ld < 4; ++ld) {
      const int r = ld * 64 + sr;
      const size_t gA = (size_t)(row0 + r) * Dc + d0 + csrc * 8;
      const size_t gB = (size_t)(n0 + r) * Dc + d0 + csrc * 8;
      const int lo = r * 64 + sc * 8;
      __builtin_amdgcn_global_load_lds((const gu32*)(xh + gA), (lu32*)(Ab + lo), 16, 0, 0);
      __builtin_amdgcn_global_load_lds((const gu32*)(chh + gB), (lu32*)(Bb + lo), 16, 0, 0);
    }
  };

  // prologue: 2 tiles in flight, gate tile 0 only (8 newest stay in flight)
  stage(0);
  stage(1);
  asm volatile("s_waitcnt vmcnt(8)" ::: "memory");
  __builtin_amdgcn_sched_barrier(0);
  __builtin_amdgcn_s_barrier();

  for (int kt = 0; kt < NT; ++kt) {
    const int p = kt & 1;
    const _Float16* Ab = smem + p * 16384;
    const _Float16* Bb = smem + 32768 + p * 16384;
#pragma unroll
    for (int ks = 0; ks < 2; ++ks) {
      const int co = ((ks * 4 + kq) ^ sw) * 8;  // swizzled 16B chunk offset (f16)
      f16x8 a[4], b[8];
#pragma unroll
      for (int i = 0; i < 4; ++i)
        a[i] = *(const f16x8*)&Ab[(wm * 64 + 16 * i + fr) * 64 + co];
#pragma unroll
      for (int j = 0; j < 8; ++j)
        b[j] = *(const f16x8*)&Bb[(wn * 128 + 16 * j + fr) * 64 + co];
      __builtin_amdgcn_s_setprio(1);
#pragma unroll
      for (int i = 0; i < 4; ++i)
#pragma unroll
        for (int j = 0; j < 8; ++j)
          acc[i][j] = __builtin_amdgcn_mfma_f32_16x16x32_f16(a[i], b[j], acc[i][j], 0, 0, 0);
      __builtin_amdgcn_s_setprio(0);
    }
    // B1: all waves done reading buf p (ds_reads consumed by MFMA => serviced)
    __builtin_amdgcn_s_barrier();
    if (kt + 2 < NT) {
      stage(kt + 2);  // overwrites buf p — safe: all reads of tile kt done
      asm volatile("s_waitcnt vmcnt(8)" ::: "memory");  // tile kt+1 complete
    } else {
      asm volatile("s_waitcnt vmcnt(0)" ::: "memory");  // drain final tile
    }
    __builtin_amdgcn_sched_barrier(0);
    // B2: acquire tile kt+1 (DMA-completed LDS visible to all)
    __builtin_amdgcn_s_barrier();
  }

  // epilogue: d~ = c2[n] - 2*dot, quantize u16 (step 1/32, offset 256),
  // LDS transpose (stride TS) to fully-coalesced 16B stores.
  float c2v[8];
#pragma unroll
  for (int j = 0; j < 8; ++j) c2v[j] = c2h[n0 + wn * 128 + 16 * j + fr];

#pragma unroll
  for (int i = 0; i < 4; ++i) {
#pragma unroll
    for (int reg = 0; reg < 4; ++reg) {
      const int lrow = wm * 64 + 16 * i + 4 * kq + reg;
#pragma unroll
      for (int j = 0; j < 8; ++j) {
        const float d = c2v[j] - 2.0f * acc[i][j][reg];
        int u = __float2int_rn((d + 256.0f) * 32.0f);
        u = min(65535, max(0, u));
        t[lrow * TS + wn * 128 + 16 * j + fr] = (unsigned short)u;
      }
    }
  }
  __syncthreads();
#pragma unroll
  for (int cc = 0; cc < 16; ++cc) {
    const int chk = cc * 512 + tid;
    const int r = chk >> 5, c16 = chk & 31;
    uint4 v = *(const uint4*)&t[r * TS + c16 * 8];
    *(uint4*)&dq[(size_t)(row0 + r) * NHALF + n0 + c16 * 8] = v;
  }
}

// ---------- fused scan+refine: one wave per (row, half), NO atomics ----------
__global__ __launch_bounds__(256) void scan_refine_kernel(
    const unsigned short* __restrict__ dq, const unsigned* __restrict__ wthr,
    const float* __restrict__ x, const float* __restrict__ centers,
    int halfbase, int mode, u64* __restrict__ best) {
  const int w = threadIdx.x >> 6, l = threadIdx.x & 63;
  const int row = blockIdx.x * 4 + w;
  const unsigned short* dr = dq + (size_t)row * NHALF;

  uint4 v[4];
#pragma unroll
  for (int k = 0; k < 4; ++k) v[k] = *(const uint4*)&dr[k * 512 + l * 8];

  // wave min of this row-half
  unsigned mn = 0xFFFFu;
#pragma unroll
  for (int k = 0; k < 4; ++k) {
    const unsigned* u = (const unsigned*)&v[k];
#pragma unroll
    for (int q = 0; q < 4; ++q) {
      mn = min(mn, u[q] & 0xFFFFu);
      mn = min(mn, u[q] >> 16);
    }
  }
#pragma unroll
  for (int m = 1; m < 64; m <<= 1) mn = min(mn, (unsigned)__shfl_xor((int)mn, m, 64));
  const unsigned thr = mn + wthr[row];

  // preload x row (fp32), 8 elems/lane
  const float* xr = x + (size_t)row * Dc + l * 8;
  float4 a0 = *(const float4*)xr, a1 = *(const float4*)(xr + 4);
  const float xa[8] = {a0.x, a0.y, a0.z, a0.w, a1.x, a1.y, a1.z, a1.w};
  double xq[8];
#pragma unroll
  for (int i = 0; i < 8; ++i) xq[i] = (double)(xa[i] + EPSF);  // fp32 x+eps, as reference

  u64 bk = ~0ULL;
  // ballot over the 32 per-lane slots; every hit gets a 64-lane fp64 dot
#pragma unroll
  for (int k = 0; k < 4; ++k) {
    const unsigned* u = (const unsigned*)&v[k];
#pragma unroll
    for (int t = 0; t < 8; ++t) {
      const unsigned uv = (u[t >> 1] >> ((t & 1) * 16)) & 0xFFFFu;
      u64 m = __ballot(uv <= thr);
      while (m) {
        const int ln = __ffsll((long long)m) - 1;
        m &= m - 1;
        const int g = halfbase + k * 512 + ln * 8 + t;
        const float* cr = centers + (size_t)g * Dc + l * 8;
        float4 b0 = *(const float4*)cr, b1 = *(const float4*)(cr + 4);
        const float ca[8] = {b0.x, b0.y, b0.z, b0.w, b1.x, b1.y, b1.z, b1.w};
        double s = 0.0;
#pragma unroll
        for (int i = 0; i < 8; ++i) {
          const double cd = (double)ca[i];
          s += cd * cd - 2.0 * xq[i] * cd;
        }
#pragma unroll
        for (int mm = 1; mm < 64; mm <<= 1) s += __shfl_xor(s, mm, 64);
        // sortable key: d2' shifted positive (|d2'| << 16384), low 12 bits = idx
        const u64 key =
            ((u64)__double_as_longlong(s + 16384.0) & ~0xFFFULL) | (unsigned)g;
        bk = min(bk, key);
      }
    }
  }
  if (l == 0) {
    if (mode) bk = min(bk, best[row]);
    best[row] = bk;
  }
}

// ---------- projection: out = centers[best] @ W + b  (f16 MFMA, 2-phase dbuf) ----------
__global__ __launch_bounds__(256, 2) void proj_mfma_kernel(
    const _Float16* __restrict__ ch, const u64* __restrict__ best,
    const _Float16* __restrict__ whT, const float* __restrict__ bias,
    float* __restrict__ out) {
  constexpr int BM = 128, BN = 128, BK = 32;
  constexpr int BUF = BM * BK + BN * BK;            // 8192 f16 per buffer
  __shared__ __align__(16) _Float16 smem[2 * BUF];  // 32 KB
  __shared__ int ssel[BM];

  const int tid = threadIdx.x;
  const int lane = tid & 63, w = tid >> 6;
  const int row0 = blockIdx.x * BM;
  const int n0 = blockIdx.y * BN;
  const int srow = w * 16 + (lane >> 2);
  const int scol = (lane & 3) * 8;
  const int fr = lane & 15, kq = lane >> 4;
  const int m0 = w * 32;

  if (tid < BM) ssel[tid] = (int)(best[row0 + tid] & 0xFFFULL);
  __syncthreads();

  f32x4 acc[2][8];
#pragma unroll
  for (int i = 0; i < 2; ++i)
#pragma unroll
    for (int j = 0; j < 8; ++j) acc[i][j] = (f32x4){0.f, 0.f, 0.f, 0.f};

  auto stage = [&](int buf, int d0) {
    _Float16* sA_ = smem + buf * BUF;
    _Float16* sB_ = sA_ + BM * BK;
#pragma unroll
    for (int r = 0; r < 2; ++r) {
      const int rr = r * 64 + srow;
      const size_t gA = (size_t)ssel[rr] * Dc + d0 + scol;
      const size_t gB = (size_t)(n0 + rr) * Dc + d0 + scol;
      const int lo = rr * BK + scol;
      __builtin_amdgcn_global_load_lds((const gu32*)(ch + gA), (lu32*)(sA_ + lo), 16, 0, 0);
      __builtin_amdgcn_global_load_lds((const gu32*)(whT + gB), (lu32*)(sB_ + lo), 16, 0, 0);
    }
  };

  constexpr int NSTEP = Dc / BK;  // 16
  stage(0, 0);
  __syncthreads();  // buf0 ready
  int cur = 0;
  for (int step = 0; step < NSTEP; ++step) {
    if (step + 1 < NSTEP) stage(cur ^ 1, (step + 1) * BK);

    const _Float16* sA = smem + cur * BUF;
    const _Float16* sB = sA + BM * BK;
    f16x8 a[2], b[8];
#pragma unroll
    for (int i = 0; i < 2; ++i)
      a[i] = *(const f16x8*)&sA[(m0 + 16 * i + fr) * BK + kq * 8];
#pragma unroll
    for (int j = 0; j < 8; ++j)
      b[j] = *(const f16x8*)&sB[(16 * j + fr) * BK + kq * 8];
#pragma unroll
    for (int i = 0; i < 2; ++i)
#pragma unroll
      for (int j = 0; j < 8; ++j)
        acc[i][j] = __builtin_amdgcn_mfma_f32_16x16x32_f16(a[i], b[j], acc[i][j], 0, 0, 0);

    __syncthreads();
    cur ^= 1;
  }

#pragma unroll
  for (int j = 0; j < 8; ++j) {
    const int col = n0 + 16 * j + fr;
    const float bb = bias[col];
#pragma unroll
    for (int i = 0; i < 2; ++i)
#pragma unroll
      for (int reg = 0; reg < 4; ++reg)
        out[(size_t)(row0 + m0 + 16 * i + 4 * kq + reg) * DOc + col] =
            acc[i][j][reg] + bb;
  }
}

extern "C" void kernel_launch(void* const* d_in, const int* in_sizes, int n_in,
                              void* d_out, int out_size, void* d_ws, size_t ws_size,
                              hipStream_t stream) {
  const float* x = (const float*)d_in[0];        // [4,4096,512]
  const float* centers = (const float*)d_in[1];  // [4096,512]
  const float* W = (const float*)d_in[2];        // [512,1024]
  const float* b = (const float*)d_in[3];        // [1024]
  float* out = (float*)d_out;                    // [4,4096,1024] fp32

  // dq (u16 [16384][2048] = 67.1 MB) lives in d_out; proj overwrites it last.
  unsigned short* dq = (unsigned short*)d_out;

  // workspace (~22.3 MB)
  char* ws = (char*)d_ws;
  _Float16* xh = (_Float16*)(ws);                 // 16.78 MB
  _Float16* ch = (_Float16*)(ws + 16777216);      // 4.19 MB
  _Float16* whT = (_Float16*)(ws + 20971520);     // 1.05 MB
  float* c2 = (float*)(ws + 22020096);            // 16 KB
  unsigned* wthr = (unsigned*)(ws + 22036480);    // 64 KB
  u64* best = (u64*)(ws + 22102016);              // 128 KB

  cvt_x_kernel<<<Mc / 4, 256, 0, stream>>>(x, xh, wthr);
  cvt_c_kernel<<<Kc / 4, 256, 0, stream>>>(centers, ch, c2);
  cvt_w_kernel<<<Dc * DOc / (256 * 8), 256, 0, stream>>>(W, whT);

  for (int half = 0; half < 2; ++half) {
    const int hb = half * NHALF;
    dist_hh_kernel<<<dim3(NHALF / 256, Mc / 256), 512, 0, stream>>>(
        xh, ch + (size_t)hb * Dc, c2 + hb, dq);
    scan_refine_kernel<<<Mc / 4, 256, 0, stream>>>(dq, wthr, x, centers, hb,
                                                   half, best);
  }
  proj_mfma_kernel<<<dim3(Mc / 128, DOc / 128), 256, 0, stream>>>(ch, best, whT, b, out);
}

// Round 3
// 268.298 us; speedup vs baseline: 1.0710x; 1.0153x over previous
//
#include <hip/hip_runtime.h>
#include <float.h>
#include <stdint.h>

#define EPSF 1e-6f

constexpr int Dc = 512, Kc = 4096, DOc = 1024;
constexpr int Mc = 16384;                 // 4*4096 rows
constexpr int NHALF = 2048;               // centers per half-pass

typedef _Float16 f16x8 __attribute__((ext_vector_type(8)));
typedef float f32x4 __attribute__((ext_vector_type(4)));
typedef __attribute__((address_space(1))) unsigned int gu32;
typedef __attribute__((address_space(3))) unsigned int lu32;
typedef unsigned long long u64;

// ---------- convert x: f16 cast + per-row candidate window ----------
__global__ __launch_bounds__(256) void cvt_x_kernel(const float* __restrict__ x,
                                                    _Float16* __restrict__ xh,
                                                    unsigned* __restrict__ wthr) {
  const int lane = threadIdx.x & 63, w = threadIdx.x >> 6;
  const int row = blockIdx.x * 4 + w;
  const size_t base = (size_t)row * Dc + lane * 8;
  float4 v0 = *(const float4*)(x + base);
  float4 v1 = *(const float4*)(x + base + 4);
  float v[8] = {v0.x, v0.y, v0.z, v0.w, v1.x, v1.y, v1.z, v1.w};
  f16x8 h;
  float s = 0.f;
#pragma unroll
  for (int i = 0; i < 8; ++i) {
    const float q = v[i] + EPSF;
    h[i] = (_Float16)q;
    s += q * q;
  }
  *(f16x8*)(xh + base) = h;
#pragma unroll
  for (int m = 1; m < 64; m <<= 1) s += __shfl_xor(s, m, 64);
  // window (u16 quant units): 64*[2(2e+e^2)*||c||max*||x||] + slack; e=2^-11
  if (lane == 0) wthr[row] = (unsigned)(2.829f * sqrtf(s) + 8.0f);
}

__global__ __launch_bounds__(256) void cvt_c_kernel(const float* __restrict__ centers,
                                                    _Float16* __restrict__ ch,
                                                    float* __restrict__ c2) {
  const int lane = threadIdx.x & 63, w = threadIdx.x >> 6;
  const int row = blockIdx.x * 4 + w;
  const size_t base = (size_t)row * Dc + lane * 8;
  float4 v0 = *(const float4*)(centers + base);
  float4 v1 = *(const float4*)(centers + base + 4);
  float v[8] = {v0.x, v0.y, v0.z, v0.w, v1.x, v1.y, v1.z, v1.w};
  f16x8 h;
  float s = 0.f;
#pragma unroll
  for (int i = 0; i < 8; ++i) { s += v[i] * v[i]; h[i] = (_Float16)v[i]; }
  *(f16x8*)(ch + base) = h;
#pragma unroll
  for (int off = 32; off > 0; off >>= 1) s += __shfl_down(s, off, 64);
  if (lane == 0) c2[row] = s;
}

__global__ __launch_bounds__(256) void cvt_w_kernel(const float* __restrict__ W,
                                                    _Float16* __restrict__ whT) {
  const int g = blockIdx.x * 256 + threadIdx.x;
  const int n = g & (DOc - 1), d8 = g >> 10;
  f16x8 h;
#pragma unroll
  for (int r = 0; r < 8; ++r) h[r] = (_Float16)W[(size_t)(d8 * 8 + r) * DOc + n];
  *(f16x8*)(whT + (size_t)n * Dc + d8 * 8) = h;
}

// ---------- distance GEMM: 256x256, BK=64, 4-sub-phase interleave ----------
// T1: XCD-aware block swizzle (8-row x 8-col panel per XCD, bijective 512=8*64).
// T2: 16B-chunk XOR swizzle (verified: 0 bank conflicts).
// T3-lite: per-K-tile 4 sub-phases {4-8 ds_read; barrier; lgkm(0); setprio;
//          16 MFMA; setprio; barrier} — m201 rhythm, m196's "fine interleave".
// T4: stage(t+2) burst between tiles, gate vmcnt(8) (never 0 in main loop).
__global__ __launch_bounds__(512, 2) void dist_hh_kernel(
    const _Float16* __restrict__ xh, const _Float16* __restrict__ chh,
    const float* __restrict__ c2h, unsigned short* __restrict__ dq) {
  constexpr int BM = 256, BN = 256, BK = 64;
  constexpr int NT = Dc / BK;  // 8 K-tiles
  constexpr int TS = 264;      // epilogue u16 row stride (528B, 16B-aligned)
  __shared__ __align__(16) char smem_raw[256 * TS * 2];
  _Float16* smem = (_Float16*)smem_raw;
  unsigned short* t = (unsigned short*)smem_raw;

  const int tid = threadIdx.x;  // 0..511
  const int lane = tid & 63;
  const int wid = tid >> 6;               // 0..7
  const int wm = wid >> 1, wn = wid & 1;  // 4(M) x 2(N) wave grid
  const int fr = lane & 15, kq = lane >> 4;

  // T1: XCD swizzle. HW round-robins linear block id across 8 XCDs; give each
  // XCD a contiguous 8(row)x8(col) panel so A-panel + B-half fit its L2.
  const int fid = blockIdx.x;
  const int swz = (fid & 7) * 64 + (fid >> 3);
  const int row0 = (swz >> 3) * BM;  // 64 row-panels
  const int n0 = (swz & 7) * BN;     // 8 col-panels

  // staging decomposition: 512 threads cover 64 rows x 8 chunks (16B) per round
  const int sr = tid >> 3;         // row within 64-row round
  const int sc = tid & 7;          // dest chunk col
  const int csrc = sc ^ (sr & 7);  // pre-swizzled source chunk col
  const int sw = fr & 7;           // read-side swizzle constant

  f32x4 acc[4][8];
#pragma unroll
  for (int i = 0; i < 4; ++i)
#pragma unroll
    for (int j = 0; j < 8; ++j) acc[i][j] = (f32x4){0.f, 0.f, 0.f, 0.f};

  auto stage = [&](int kt) {
    const int p = kt & 1;
    const int d0 = kt * BK;
    _Float16* Ab = smem + p * 16384;
    _Float16* Bb = smem + 32768 + p * 16384;
#pragma unroll
    for (int ld = 0; ld < 4; ++ld) {
      const int r = ld * 64 + sr;
      const size_t gA = (size_t)(row0 + r) * Dc + d0 + csrc * 8;
      const size_t gB = (size_t)(n0 + r) * Dc + d0 + csrc * 8;
      const int lo = r * 64 + sc * 8;
      __builtin_amdgcn_global_load_lds((const gu32*)(xh + gA), (lu32*)(Ab + lo), 16, 0, 0);
      __builtin_amdgcn_global_load_lds((const gu32*)(chh + gB), (lu32*)(Bb + lo), 16, 0, 0);
    }
  };

  // prologue: 2 tiles in flight, gate tile 0 only (8 newest stay in flight)
  stage(0);
  stage(1);
  asm volatile("s_waitcnt vmcnt(8)" ::: "memory");
  __builtin_amdgcn_sched_barrier(0);
  __builtin_amdgcn_s_barrier();

  for (int kt = 0; kt < NT; ++kt) {
    const int p = kt & 1;
    const _Float16* Ab = smem + p * 16384;
    const _Float16* Bb = smem + 32768 + p * 16384;
    f16x8 a[4], b[4];
#pragma unroll
    for (int s = 0; s < 4; ++s) {  // (kh, nh): sub-phase = 16-MFMA cluster
      const int kh = s >> 1, nh = s & 1;
      const int co = ((kh * 4 + kq) ^ sw) * 8;  // swizzled 16B chunk (f16 idx)
      if (nh == 0) {
#pragma unroll
        for (int m = 0; m < 4; ++m)
          a[m] = *(const f16x8*)&Ab[(wm * 64 + 16 * m + fr) * 64 + co];
      }
#pragma unroll
      for (int n = 0; n < 4; ++n)
        b[n] = *(const f16x8*)&Bb[(wn * 128 + nh * 64 + 16 * n + fr) * 64 + co];
      __builtin_amdgcn_s_barrier();
      asm volatile("s_waitcnt lgkmcnt(0)" ::: "memory");
      __builtin_amdgcn_s_setprio(1);
#pragma unroll
      for (int m = 0; m < 4; ++m)
#pragma unroll
        for (int n = 0; n < 4; ++n)
          acc[m][nh * 4 + n] =
              __builtin_amdgcn_mfma_f32_16x16x32_f16(a[m], b[n], acc[m][nh * 4 + n], 0, 0, 0);
      __builtin_amdgcn_s_setprio(0);
      __builtin_amdgcn_s_barrier();
    }
    // inter-tile: slot p free (all reads serviced before waves' MFMAs + barrier)
    if (kt + 2 < NT) {
      stage(kt + 2);  // overwrites slot p
      asm volatile("s_waitcnt vmcnt(8)" ::: "memory");  // tile kt+1 landed
    } else {
      asm volatile("s_waitcnt vmcnt(0)" ::: "memory");  // drain final tile
    }
    __builtin_amdgcn_sched_barrier(0);
    __builtin_amdgcn_s_barrier();  // acquire: DMA-completed LDS visible to all
  }

  // epilogue: d~ = c2[n] - 2*dot, quantize u16 (step 1/32, offset 256),
  // LDS transpose (stride TS) to fully-coalesced 16B stores.
  float c2v[8];
#pragma unroll
  for (int j = 0; j < 8; ++j) c2v[j] = c2h[n0 + wn * 128 + 16 * (j & 3) + (j >> 2) * 64 + fr];

#pragma unroll
  for (int i = 0; i < 4; ++i) {
#pragma unroll
    for (int reg = 0; reg < 4; ++reg) {
      const int lrow = wm * 64 + 16 * i + 4 * kq + reg;
#pragma unroll
      for (int j = 0; j < 8; ++j) {
        // acc[i][j]: j = nh*4+n -> col = wn*128 + nh*64 + 16*n + fr
        const int col = wn * 128 + (j >> 2) * 64 + 16 * (j & 3) + fr;
        const float d = c2v[j] - 2.0f * acc[i][j][reg];
        int u = __float2int_rn((d + 256.0f) * 32.0f);
        u = min(65535, max(0, u));
        t[lrow * TS + col] = (unsigned short)u;
      }
    }
  }
  __syncthreads();
#pragma unroll
  for (int cc = 0; cc < 16; ++cc) {
    const int chk = cc * 512 + tid;
    const int r = chk >> 5, c16 = chk & 31;
    uint4 v = *(const uint4*)&t[r * TS + c16 * 8];
    *(uint4*)&dq[(size_t)(row0 + r) * NHALF + n0 + c16 * 8] = v;
  }
}

// ---------- fused scan+refine: one wave per (row, half), NO atomics ----------
__global__ __launch_bounds__(256) void scan_refine_kernel(
    const unsigned short* __restrict__ dq, const unsigned* __restrict__ wthr,
    const float* __restrict__ x, const float* __restrict__ centers,
    int halfbase, int mode, u64* __restrict__ best) {
  const int w = threadIdx.x >> 6, l = threadIdx.x & 63;
  const int row = blockIdx.x * 4 + w;
  const unsigned short* dr = dq + (size_t)row * NHALF;

  uint4 v[4];
#pragma unroll
  for (int k = 0; k < 4; ++k) v[k] = *(const uint4*)&dr[k * 512 + l * 8];

  // wave min of this row-half
  unsigned mn = 0xFFFFu;
#pragma unroll
  for (int k = 0; k < 4; ++k) {
    const unsigned* u = (const unsigned*)&v[k];
#pragma unroll
    for (int q = 0; q < 4; ++q) {
      mn = min(mn, u[q] & 0xFFFFu);
      mn = min(mn, u[q] >> 16);
    }
  }
#pragma unroll
  for (int m = 1; m < 64; m <<= 1) mn = min(mn, (unsigned)__shfl_xor((int)mn, m, 64));
  const unsigned thr = mn + wthr[row];

  // preload x row (fp32), 8 elems/lane
  const float* xr = x + (size_t)row * Dc + l * 8;
  float4 a0 = *(const float4*)xr, a1 = *(const float4*)(xr + 4);
  const float xa[8] = {a0.x, a0.y, a0.z, a0.w, a1.x, a1.y, a1.z, a1.w};
  double xq[8];
#pragma unroll
  for (int i = 0; i < 8; ++i) xq[i] = (double)(xa[i] + EPSF);  // fp32 x+eps, as reference

  u64 bk = ~0ULL;
  // ballot over the 32 per-lane slots; every hit gets a 64-lane fp64 dot
#pragma unroll
  for (int k = 0; k < 4; ++k) {
    const unsigned* u = (const unsigned*)&v[k];
#pragma unroll
    for (int t = 0; t < 8; ++t) {
      const unsigned uv = (u[t >> 1] >> ((t & 1) * 16)) & 0xFFFFu;
      u64 m = __ballot(uv <= thr);
      while (m) {
        const int ln = __ffsll((long long)m) - 1;
        m &= m - 1;
        const int g = halfbase + k * 512 + ln * 8 + t;
        const float* cr = centers + (size_t)g * Dc + l * 8;
        float4 b0 = *(const float4*)cr, b1 = *(const float4*)(cr + 4);
        const float ca[8] = {b0.x, b0.y, b0.z, b0.w, b1.x, b1.y, b1.z, b1.w};
        double s = 0.0;
#pragma unroll
        for (int i = 0; i < 8; ++i) {
          const double cd = (double)ca[i];
          s += cd * cd - 2.0 * xq[i] * cd;
        }
#pragma unroll
        for (int mm = 1; mm < 64; mm <<= 1) s += __shfl_xor(s, mm, 64);
        // sortable key: d2' shifted positive (|d2'| << 16384), low 12 bits = idx
        const u64 key =
            ((u64)__double_as_longlong(s + 16384.0) & ~0xFFFULL) | (unsigned)g;
        bk = min(bk, key);
      }
    }
  }
  if (l == 0) {
    if (mode) bk = min(bk, best[row]);
    best[row] = bk;
  }
}

// ---------- projection: out = centers[best] @ W + b  (f16 MFMA, 2-phase dbuf) ----------
__global__ __launch_bounds__(256, 2) void proj_mfma_kernel(
    const _Float16* __restrict__ ch, const u64* __restrict__ best,
    const _Float16* __restrict__ whT, const float* __restrict__ bias,
    float* __restrict__ out) {
  constexpr int BM = 128, BN = 128, BK = 32;
  constexpr int BUF = BM * BK + BN * BK;            // 8192 f16 per buffer
  __shared__ __align__(16) _Float16 smem[2 * BUF];  // 32 KB
  __shared__ int ssel[BM];

  const int tid = threadIdx.x;
  const int lane = tid & 63, w = tid >> 6;
  const int row0 = blockIdx.x * BM;
  const int n0 = blockIdx.y * BN;
  const int srow = w * 16 + (lane >> 2);
  const int scol = (lane & 3) * 8;
  const int fr = lane & 15, kq = lane >> 4;
  const int m0 = w * 32;

  if (tid < BM) ssel[tid] = (int)(best[row0 + tid] & 0xFFFULL);
  __syncthreads();

  f32x4 acc[2][8];
#pragma unroll
  for (int i = 0; i < 2; ++i)
#pragma unroll
    for (int j = 0; j < 8; ++j) acc[i][j] = (f32x4){0.f, 0.f, 0.f, 0.f};

  auto stage = [&](int buf, int d0) {
    _Float16* sA_ = smem + buf * BUF;
    _Float16* sB_ = sA_ + BM * BK;
#pragma unroll
    for (int r = 0; r < 2; ++r) {
      const int rr = r * 64 + srow;
      const size_t gA = (size_t)ssel[rr] * Dc + d0 + scol;
      const size_t gB = (size_t)(n0 + rr) * Dc + d0 + scol;
      const int lo = rr * BK + scol;
      __builtin_amdgcn_global_load_lds((const gu32*)(ch + gA), (lu32*)(sA_ + lo), 16, 0, 0);
      __builtin_amdgcn_global_load_lds((const gu32*)(whT + gB), (lu32*)(sB_ + lo), 16, 0, 0);
    }
  };

  constexpr int NSTEP = Dc / BK;  // 16
  stage(0, 0);
  __syncthreads();  // buf0 ready
  int cur = 0;
  for (int step = 0; step < NSTEP; ++step) {
    if (step + 1 < NSTEP) stage(cur ^ 1, (step + 1) * BK);

    const _Float16* sA = smem + cur * BUF;
    const _Float16* sB = sA + BM * BK;
    f16x8 a[2], b[8];
#pragma unroll
    for (int i = 0; i < 2; ++i)
      a[i] = *(const f16x8*)&sA[(m0 + 16 * i + fr) * BK + kq * 8];
#pragma unroll
    for (int j = 0; j < 8; ++j)
      b[j] = *(const f16x8*)&sB[(16 * j + fr) * BK + kq * 8];
#pragma unroll
    for (int i = 0; i < 2; ++i)
#pragma unroll
      for (int j = 0; j < 8; ++j)
        acc[i][j] = __builtin_amdgcn_mfma_f32_16x16x32_f16(a[i], b[j], acc[i][j], 0, 0, 0);

    __syncthreads();
    cur ^= 1;
  }

#pragma unroll
  for (int j = 0; j < 8; ++j) {
    const int col = n0 + 16 * j + fr;
    const float bb = bias[col];
#pragma unroll
    for (int i = 0; i < 2; ++i)
#pragma unroll
      for (int reg = 0; reg < 4; ++reg)
        out[(size_t)(row0 + m0 + 16 * i + 4 * kq + reg) * DOc + col] =
            acc[i][j][reg] + bb;
  }
}

extern "C" void kernel_launch(void* const* d_in, const int* in_sizes, int n_in,
                              void* d_out, int out_size, void* d_ws, size_t ws_size,
                              hipStream_t stream) {
  const float* x = (const float*)d_in[0];        // [4,4096,512]
  const float* centers = (const float*)d_in[1];  // [4096,512]
  const float* W = (const float*)d_in[2];        // [512,1024]
  const float* b = (const float*)d_in[3];        // [1024]
  float* out = (float*)d_out;                    // [4,4096,1024] fp32

  // dq (u16 [16384][2048] = 67.1 MB) lives in d_out; proj overwrites it last.
  unsigned short* dq = (unsigned short*)d_out;

  // workspace (~22.3 MB)
  char* ws = (char*)d_ws;
  _Float16* xh = (_Float16*)(ws);                 // 16.78 MB
  _Float16* ch = (_Float16*)(ws + 16777216);      // 4.19 MB
  _Float16* whT = (_Float16*)(ws + 20971520);     // 1.05 MB
  float* c2 = (float*)(ws + 22020096);            // 16 KB
  unsigned* wthr = (unsigned*)(ws + 22036480);    // 64 KB
  u64* best = (u64*)(ws + 22102016);              // 128 KB

  cvt_x_kernel<<<Mc / 4, 256, 0, stream>>>(x, xh, wthr);
  cvt_c_kernel<<<Kc / 4, 256, 0, stream>>>(centers, ch, c2);
  cvt_w_kernel<<<Dc * DOc / (256 * 8), 256, 0, stream>>>(W, whT);

  for (int half = 0; half < 2; ++half) {
    const int hb = half * NHALF;
    dist_hh_kernel<<<(Mc / 256) * (NHALF / 256), 512, 0, stream>>>(
        xh, ch + (size_t)hb * Dc, c2 + hb, dq);
    scan_refine_kernel<<<Mc / 4, 256, 0, stream>>>(dq, wthr, x, centers, hb,
                                                   half, best);
  }
  proj_mfma_kernel<<<dim3(Mc / 128, DOc / 128), 256, 0, stream>>>(ch, best, whT, b, out);
}

// Round 4
// 263.893 us; speedup vs baseline: 1.0888x; 1.0167x over previous
//
#include <hip/hip_runtime.h>
#include <float.h>
#include <stdint.h>

#define EPSF 1e-6f

constexpr int Dc = 512, Kc = 4096, DOc = 1024;
constexpr int Mc = 16384;                 // 4*4096 rows
constexpr int NHALF = 2048;               // centers per half-pass

typedef _Float16 f16x8 __attribute__((ext_vector_type(8)));
typedef float f32x4 __attribute__((ext_vector_type(4)));
typedef __attribute__((address_space(1))) unsigned int gu32;
typedef __attribute__((address_space(3))) unsigned int lu32;
typedef unsigned long long u64;

// ---------- fused converts: x (f16 + window), centers (f16 + c2), W^T ----------
__global__ __launch_bounds__(256) void cvt_all_kernel(
    const float* __restrict__ x, _Float16* __restrict__ xh, unsigned* __restrict__ wthr,
    const float* __restrict__ centers, _Float16* __restrict__ ch, float* __restrict__ c2,
    const float* __restrict__ W, _Float16* __restrict__ whT) {
  const int bid = blockIdx.x;
  const int lane = threadIdx.x & 63, w = threadIdx.x >> 6;
  if (bid < Mc / 4) {
    const int row = bid * 4 + w;
    const size_t base = (size_t)row * Dc + lane * 8;
    float4 v0 = *(const float4*)(x + base);
    float4 v1 = *(const float4*)(x + base + 4);
    float v[8] = {v0.x, v0.y, v0.z, v0.w, v1.x, v1.y, v1.z, v1.w};
    f16x8 h;
    float s = 0.f;
#pragma unroll
    for (int i = 0; i < 8; ++i) {
      const float q = v[i] + EPSF;
      h[i] = (_Float16)q;
      s += q * q;
    }
    *(f16x8*)(xh + base) = h;
#pragma unroll
    for (int m = 1; m < 64; m <<= 1) s += __shfl_xor(s, m, 64);
    // window (u16 quant units): 64*[2(2e+e^2)*||c||max*||x||] + slack; e=2^-11
    if (lane == 0) wthr[row] = (unsigned)(2.829f * sqrtf(s) + 8.0f);
  } else if (bid < Mc / 4 + Kc / 4) {
    const int row = (bid - Mc / 4) * 4 + w;
    const size_t base = (size_t)row * Dc + lane * 8;
    float4 v0 = *(const float4*)(centers + base);
    float4 v1 = *(const float4*)(centers + base + 4);
    float v[8] = {v0.x, v0.y, v0.z, v0.w, v1.x, v1.y, v1.z, v1.w};
    f16x8 h;
    float s = 0.f;
#pragma unroll
    for (int i = 0; i < 8; ++i) { s += v[i] * v[i]; h[i] = (_Float16)v[i]; }
    *(f16x8*)(ch + base) = h;
#pragma unroll
    for (int off = 32; off > 0; off >>= 1) s += __shfl_down(s, off, 64);
    if (lane == 0) c2[row] = s;
  } else {
    const int g = (bid - Mc / 4 - Kc / 4) * 256 + threadIdx.x;
    const int n = g & (DOc - 1), d8 = g >> 10;
    f16x8 h;
#pragma unroll
    for (int r = 0; r < 8; ++r) h[r] = (_Float16)W[(size_t)(d8 * 8 + r) * DOc + n];
    *(f16x8*)(whT + (size_t)n * Dc + d8 * 8) = h;
  }
}

// ---------- distance GEMM: 256x256, BK=64, 4-sub-phase interleave ----------
// (unchanged from round 3: T1 XCD swizzle, T2 swizzle 0-conflict, sub-phase
//  rhythm, vmcnt(8) gate. Verified passing; kept byte-identical.)
__global__ __launch_bounds__(512, 2) void dist_hh_kernel(
    const _Float16* __restrict__ xh, const _Float16* __restrict__ chh,
    const float* __restrict__ c2h, unsigned short* __restrict__ dq) {
  constexpr int BM = 256, BN = 256, BK = 64;
  constexpr int NT = Dc / BK;  // 8 K-tiles
  constexpr int TS = 264;      // epilogue u16 row stride (528B, 16B-aligned)
  __shared__ __align__(16) char smem_raw[256 * TS * 2];
  _Float16* smem = (_Float16*)smem_raw;
  unsigned short* t = (unsigned short*)smem_raw;

  const int tid = threadIdx.x;  // 0..511
  const int lane = tid & 63;
  const int wid = tid >> 6;               // 0..7
  const int wm = wid >> 1, wn = wid & 1;  // 4(M) x 2(N) wave grid
  const int fr = lane & 15, kq = lane >> 4;

  const int fid = blockIdx.x;
  const int swz = (fid & 7) * 64 + (fid >> 3);
  const int row0 = (swz >> 3) * BM;  // 64 row-panels
  const int n0 = (swz & 7) * BN;     // 8 col-panels

  const int sr = tid >> 3;         // row within 64-row round
  const int sc = tid & 7;          // dest chunk col
  const int csrc = sc ^ (sr & 7);  // pre-swizzled source chunk col
  const int sw = fr & 7;           // read-side swizzle constant

  f32x4 acc[4][8];
#pragma unroll
  for (int i = 0; i < 4; ++i)
#pragma unroll
    for (int j = 0; j < 8; ++j) acc[i][j] = (f32x4){0.f, 0.f, 0.f, 0.f};

  auto stage = [&](int kt) {
    const int p = kt & 1;
    const int d0 = kt * BK;
    _Float16* Ab = smem + p * 16384;
    _Float16* Bb = smem + 32768 + p * 16384;
#pragma unroll
    for (int ld = 0; ld < 4; ++ld) {
      const int r = ld * 64 + sr;
      const size_t gA = (size_t)(row0 + r) * Dc + d0 + csrc * 8;
      const size_t gB = (size_t)(n0 + r) * Dc + d0 + csrc * 8;
      const int lo = r * 64 + sc * 8;
      __builtin_amdgcn_global_load_lds((const gu32*)(xh + gA), (lu32*)(Ab + lo), 16, 0, 0);
      __builtin_amdgcn_global_load_lds((const gu32*)(chh + gB), (lu32*)(Bb + lo), 16, 0, 0);
    }
  };

  stage(0);
  stage(1);
  asm volatile("s_waitcnt vmcnt(8)" ::: "memory");
  __builtin_amdgcn_sched_barrier(0);
  __builtin_amdgcn_s_barrier();

  for (int kt = 0; kt < NT; ++kt) {
    const int p = kt & 1;
    const _Float16* Ab = smem + p * 16384;
    const _Float16* Bb = smem + 32768 + p * 16384;
    f16x8 a[4], b[4];
#pragma unroll
    for (int s = 0; s < 4; ++s) {  // (kh, nh): sub-phase = 16-MFMA cluster
      const int kh = s >> 1, nh = s & 1;
      const int co = ((kh * 4 + kq) ^ sw) * 8;  // swizzled 16B chunk (f16 idx)
      if (nh == 0) {
#pragma unroll
        for (int m = 0; m < 4; ++m)
          a[m] = *(const f16x8*)&Ab[(wm * 64 + 16 * m + fr) * 64 + co];
      }
#pragma unroll
      for (int n = 0; n < 4; ++n)
        b[n] = *(const f16x8*)&Bb[(wn * 128 + nh * 64 + 16 * n + fr) * 64 + co];
      __builtin_amdgcn_s_barrier();
      asm volatile("s_waitcnt lgkmcnt(0)" ::: "memory");
      __builtin_amdgcn_s_setprio(1);
#pragma unroll
      for (int m = 0; m < 4; ++m)
#pragma unroll
        for (int n = 0; n < 4; ++n)
          acc[m][nh * 4 + n] =
              __builtin_amdgcn_mfma_f32_16x16x32_f16(a[m], b[n], acc[m][nh * 4 + n], 0, 0, 0);
      __builtin_amdgcn_s_setprio(0);
      __builtin_amdgcn_s_barrier();
    }
    if (kt + 2 < NT) {
      stage(kt + 2);
      asm volatile("s_waitcnt vmcnt(8)" ::: "memory");
    } else {
      asm volatile("s_waitcnt vmcnt(0)" ::: "memory");
    }
    __builtin_amdgcn_sched_barrier(0);
    __builtin_amdgcn_s_barrier();
  }

  float c2v[8];
#pragma unroll
  for (int j = 0; j < 8; ++j) c2v[j] = c2h[n0 + wn * 128 + 16 * (j & 3) + (j >> 2) * 64 + fr];

#pragma unroll
  for (int i = 0; i < 4; ++i) {
#pragma unroll
    for (int reg = 0; reg < 4; ++reg) {
      const int lrow = wm * 64 + 16 * i + 4 * kq + reg;
#pragma unroll
      for (int j = 0; j < 8; ++j) {
        const int col = wn * 128 + (j >> 2) * 64 + 16 * (j & 3) + fr;
        const float d = c2v[j] - 2.0f * acc[i][j][reg];
        int u = __float2int_rn((d + 256.0f) * 32.0f);
        u = min(65535, max(0, u));
        t[lrow * TS + col] = (unsigned short)u;
      }
    }
  }
  __syncthreads();
#pragma unroll
  for (int cc = 0; cc < 16; ++cc) {
    const int chk = cc * 512 + tid;
    const int r = chk >> 5, c16 = chk & 31;
    uint4 v = *(const uint4*)&t[r * TS + c16 * 8];
    *(uint4*)&dq[(size_t)(row0 + r) * NHALF + n0 + c16 * 8] = v;
  }
}

// ---------- fused scan+refine: one wave per (row, half), NO atomics ----------
__global__ __launch_bounds__(256) void scan_refine_kernel(
    const unsigned short* __restrict__ dq, const unsigned* __restrict__ wthr,
    const float* __restrict__ x, const float* __restrict__ centers,
    int halfbase, int mode, u64* __restrict__ best) {
  const int w = threadIdx.x >> 6, l = threadIdx.x & 63;
  const int row = blockIdx.x * 4 + w;
  const unsigned short* dr = dq + (size_t)row * NHALF;

  uint4 v[4];
#pragma unroll
  for (int k = 0; k < 4; ++k) v[k] = *(const uint4*)&dr[k * 512 + l * 8];

  unsigned mn = 0xFFFFu;
#pragma unroll
  for (int k = 0; k < 4; ++k) {
    const unsigned* u = (const unsigned*)&v[k];
#pragma unroll
    for (int q = 0; q < 4; ++q) {
      mn = min(mn, u[q] & 0xFFFFu);
      mn = min(mn, u[q] >> 16);
    }
  }
#pragma unroll
  for (int m = 1; m < 64; m <<= 1) mn = min(mn, (unsigned)__shfl_xor((int)mn, m, 64));
  const unsigned thr = mn + wthr[row];

  const float* xr = x + (size_t)row * Dc + l * 8;
  float4 a0 = *(const float4*)xr, a1 = *(const float4*)(xr + 4);
  const float xa[8] = {a0.x, a0.y, a0.z, a0.w, a1.x, a1.y, a1.z, a1.w};
  double xq[8];
#pragma unroll
  for (int i = 0; i < 8; ++i) xq[i] = (double)(xa[i] + EPSF);

  u64 bk = ~0ULL;
#pragma unroll
  for (int k = 0; k < 4; ++k) {
    const unsigned* u = (const unsigned*)&v[k];
#pragma unroll
    for (int t = 0; t < 8; ++t) {
      const unsigned uv = (u[t >> 1] >> ((t & 1) * 16)) & 0xFFFFu;
      u64 m = __ballot(uv <= thr);
      while (m) {
        const int ln = __ffsll((long long)m) - 1;
        m &= m - 1;
        const int g = halfbase + k * 512 + ln * 8 + t;
        const float* cr = centers + (size_t)g * Dc + l * 8;
        float4 b0 = *(const float4*)cr, b1 = *(const float4*)(cr + 4);
        const float ca[8] = {b0.x, b0.y, b0.z, b0.w, b1.x, b1.y, b1.z, b1.w};
        double s = 0.0;
#pragma unroll
        for (int i = 0; i < 8; ++i) {
          const double cd = (double)ca[i];
          s += cd * cd - 2.0 * xq[i] * cd;
        }
#pragma unroll
        for (int mm = 1; mm < 64; mm <<= 1) s += __shfl_xor(s, mm, 64);
        const u64 key =
            ((u64)__double_as_longlong(s + 16384.0) & ~0xFFFULL) | (unsigned)g;
        bk = min(bk, key);
      }
    }
  }
  if (l == 0) {
    if (mode) bk = min(bk, best[row]);
    best[row] = bk;
  }
}

// ---------- projection: out = centers[best] @ W + b  (256x256, dist skeleton) ----------
__global__ __launch_bounds__(512, 2) void proj_mfma_kernel(
    const _Float16* __restrict__ ch, const u64* __restrict__ best,
    const _Float16* __restrict__ whT, const float* __restrict__ bias,
    float* __restrict__ out) {
  constexpr int BM = 256, BN = 256, BK = 64;
  constexpr int NT = Dc / BK;  // 8 K-tiles
  __shared__ __align__(16) _Float16 smem[4 * 16384];  // 128 KB: 2 slots x (A|B)
  __shared__ int ssel[BM];

  const int tid = threadIdx.x;  // 0..511
  const int lane = tid & 63;
  const int wid = tid >> 6;
  const int wm = wid >> 1, wn = wid & 1;  // 4(M) x 2(N)
  const int fr = lane & 15, kq = lane >> 4;
  const int row0 = (blockIdx.x >> 2) * BM;   // 64 row-panels
  const int n0 = (blockIdx.x & 3) * BN;      // 4 col-panels (DOc=1024)

  const int sr = tid >> 3;
  const int sc = tid & 7;
  const int csrc = sc ^ (sr & 7);
  const int sw = fr & 7;

  if (tid < 256) ssel[tid] = (int)(best[row0 + tid] & 0xFFFULL);
  __syncthreads();

  f32x4 acc[4][8];
#pragma unroll
  for (int i = 0; i < 4; ++i)
#pragma unroll
    for (int j = 0; j < 8; ++j) acc[i][j] = (f32x4){0.f, 0.f, 0.f, 0.f};

  auto stage = [&](int kt) {
    const int p = kt & 1;
    const int d0 = kt * BK;
    _Float16* Ab = smem + p * 16384;
    _Float16* Bb = smem + 32768 + p * 16384;
#pragma unroll
    for (int ld = 0; ld < 4; ++ld) {
      const int r = ld * 64 + sr;
      const size_t gA = (size_t)ssel[r] * Dc + d0 + csrc * 8;
      const size_t gB = (size_t)(n0 + r) * Dc + d0 + csrc * 8;
      const int lo = r * 64 + sc * 8;
      __builtin_amdgcn_global_load_lds((const gu32*)(ch + gA), (lu32*)(Ab + lo), 16, 0, 0);
      __builtin_amdgcn_global_load_lds((const gu32*)(whT + gB), (lu32*)(Bb + lo), 16, 0, 0);
    }
  };

  stage(0);
  stage(1);
  asm volatile("s_waitcnt vmcnt(8)" ::: "memory");
  __builtin_amdgcn_sched_barrier(0);
  __builtin_amdgcn_s_barrier();

  for (int kt = 0; kt < NT; ++kt) {
    const int p = kt & 1;
    const _Float16* Ab = smem + p * 16384;
    const _Float16* Bb = smem + 32768 + p * 16384;
    f16x8 a[4], b[4];
#pragma unroll
    for (int s = 0; s < 4; ++s) {
      const int kh = s >> 1, nh = s & 1;
      const int co = ((kh * 4 + kq) ^ sw) * 8;
      if (nh == 0) {
#pragma unroll
        for (int m = 0; m < 4; ++m)
          a[m] = *(const f16x8*)&Ab[(wm * 64 + 16 * m + fr) * 64 + co];
      }
#pragma unroll
      for (int n = 0; n < 4; ++n)
        b[n] = *(const f16x8*)&Bb[(wn * 128 + nh * 64 + 16 * n + fr) * 64 + co];
      __builtin_amdgcn_s_barrier();
      asm volatile("s_waitcnt lgkmcnt(0)" ::: "memory");
      __builtin_amdgcn_s_setprio(1);
#pragma unroll
      for (int m = 0; m < 4; ++m)
#pragma unroll
        for (int n = 0; n < 4; ++n)
          acc[m][nh * 4 + n] =
              __builtin_amdgcn_mfma_f32_16x16x32_f16(a[m], b[n], acc[m][nh * 4 + n], 0, 0, 0);
      __builtin_amdgcn_s_setprio(0);
      __builtin_amdgcn_s_barrier();
    }
    if (kt + 2 < NT) {
      stage(kt + 2);
      asm volatile("s_waitcnt vmcnt(8)" ::: "memory");
    } else {
      asm volatile("s_waitcnt vmcnt(0)" ::: "memory");
    }
    __builtin_amdgcn_sched_barrier(0);
    __builtin_amdgcn_s_barrier();
  }

  // epilogue: direct f32 stores + bias
#pragma unroll
  for (int j = 0; j < 8; ++j) {
    const int col = n0 + wn * 128 + (j >> 2) * 64 + 16 * (j & 3) + fr;
    const float bb = bias[col];
#pragma unroll
    for (int i = 0; i < 4; ++i)
#pragma unroll
      for (int reg = 0; reg < 4; ++reg)
        out[(size_t)(row0 + wm * 64 + 16 * i + 4 * kq + reg) * DOc + col] =
            acc[i][j][reg] + bb;
  }
}

extern "C" void kernel_launch(void* const* d_in, const int* in_sizes, int n_in,
                              void* d_out, int out_size, void* d_ws, size_t ws_size,
                              hipStream_t stream) {
  const float* x = (const float*)d_in[0];        // [4,4096,512]
  const float* centers = (const float*)d_in[1];  // [4096,512]
  const float* W = (const float*)d_in[2];        // [512,1024]
  const float* b = (const float*)d_in[3];        // [1024]
  float* out = (float*)d_out;                    // [4,4096,1024] fp32

  // dq (u16 [16384][2048] = 67.1 MB) lives in d_out; proj overwrites it last.
  unsigned short* dq = (unsigned short*)d_out;

  // workspace (~22.3 MB)
  char* ws = (char*)d_ws;
  _Float16* xh = (_Float16*)(ws);                 // 16.78 MB
  _Float16* ch = (_Float16*)(ws + 16777216);      // 4.19 MB
  _Float16* whT = (_Float16*)(ws + 20971520);     // 1.05 MB
  float* c2 = (float*)(ws + 22020096);            // 16 KB
  unsigned* wthr = (unsigned*)(ws + 22036480);    // 64 KB
  u64* best = (u64*)(ws + 22102016);              // 128 KB

  cvt_all_kernel<<<Mc / 4 + Kc / 4 + 256, 256, 0, stream>>>(x, xh, wthr, centers,
                                                            ch, c2, W, whT);

  for (int half = 0; half < 2; ++half) {
    const int hb = half * NHALF;
    dist_hh_kernel<<<(Mc / 256) * (NHALF / 256), 512, 0, stream>>>(
        xh, ch + (size_t)hb * Dc, c2 + hb, dq);
    scan_refine_kernel<<<Mc / 4, 256, 0, stream>>>(dq, wthr, x, centers, hb,
                                                   half, best);
  }
  proj_mfma_kernel<<<256, 512, 0, stream>>>(ch, best, whT, b, out);
}